// Round 1
// baseline (341.537 us; speedup 1.0000x reference)
//
#include <hip/hip_runtime.h>
#include <math.h>

#define TW 64
#define TH 32
#define HR (TH + 10)          // 42 rows of horizontal-conv results
#define BLOCK 256
#define IMG_H 512
#define IMG_W 512
#define PLANES 96             // 32 batch * 3 channels
#define NBLOCKS (PLANES * (IMG_W / TW) * (IMG_H / TH))   // 96*8*16 = 12288
#define N_TOTAL 25165824.0f   // 32*3*512*512

__device__ __forceinline__ void make_weights(float g[11]) {
    float s = 0.f;
#pragma unroll
    for (int k = 0; k < 11; ++k) {
        float d = (float)(k - 5);
        g[k] = __expf(-d * d / 4.5f);   // 2*sigma^2 = 4.5
        s += g[k];
    }
    float inv = 1.f / s;
#pragma unroll
    for (int k = 0; k < 11; ++k) g[k] *= inv;
}

__global__ __launch_bounds__(BLOCK, 2)
void ssim_main(const float* __restrict__ pred,
               const float* __restrict__ targ,
               float* __restrict__ accum) {
    // 5 horizontal-conv planes: mu1h, mu2h, p2h, t2h, pth
    __shared__ float s_h[5][HR][TW];      // 53760 B
    __shared__ float s_red[BLOCK / 64];

    float g[11];
    make_weights(g);

    const int bx    = blockIdx.x;
    const int plane = bx >> 7;            // /128 tiles per plane
    const int rem   = bx & 127;
    const int ty    = rem >> 3;           // 16 row-strips
    const int tx    = rem & 7;            // 8 col-tiles
    const int r0    = ty * TH;
    const int c0    = tx * TW;

    const float* P = pred + (size_t)plane * (IMG_H * IMG_W);
    const float* T = targ + (size_t)plane * (IMG_H * IMG_W);

    // ---------- Phase 1: horizontal conv, global -> registers -> LDS ----------
    // slot s: hr = s/8 (LDS row, global row r0-5+hr), cseg = (s%8)*8 (8 output cols)
    for (int s = threadIdx.x; s < HR * 8; s += BLOCK) {
        const int hr   = s >> 3;
        const int cseg = (s & 7) * 8;
        const int gr   = r0 - 5 + hr;

        float hp[8], ht[8], hpp[8], htt[8], hpt[8];

        if (gr < 0 || gr >= IMG_H) {
#pragma unroll
            for (int j = 0; j < 8; ++j) { hp[j]=0.f; ht[j]=0.f; hpp[j]=0.f; htt[j]=0.f; hpt[j]=0.f; }
        } else {
            // need global cols [c0+cseg-5, c0+cseg+12]; load aligned window [a, a+24)
            const int a = c0 + cseg - 8;
            const float* rowP = P + (size_t)gr * IMG_W;
            const float* rowT = T + (size_t)gr * IMG_W;
            float xp[24], xt[24];
#pragma unroll
            for (int v = 0; v < 6; ++v) {
                const int col = a + v * 4;
                if (col >= 0 && col + 3 < IMG_W) {
                    float4 fp = *(const float4*)(rowP + col);
                    float4 ft = *(const float4*)(rowT + col);
                    xp[v*4+0]=fp.x; xp[v*4+1]=fp.y; xp[v*4+2]=fp.z; xp[v*4+3]=fp.w;
                    xt[v*4+0]=ft.x; xt[v*4+1]=ft.y; xt[v*4+2]=ft.z; xt[v*4+3]=ft.w;
                } else {
                    xp[v*4+0]=0.f; xp[v*4+1]=0.f; xp[v*4+2]=0.f; xp[v*4+3]=0.f;
                    xt[v*4+0]=0.f; xt[v*4+1]=0.f; xt[v*4+2]=0.f; xt[v*4+3]=0.f;
                }
            }
            // products for local cols 3..20 (global c0+cseg-5 .. +12)
            float pp[21], tt[21], pt[21];
#pragma unroll
            for (int i = 3; i < 21; ++i) {
                pp[i] = xp[i] * xp[i];
                tt[i] = xt[i] * xt[i];
                pt[i] = xp[i] * xt[i];
            }
#pragma unroll
            for (int j = 0; j < 8; ++j) {
                float a0=0.f, a1=0.f, a2=0.f, a3=0.f, a4=0.f;
#pragma unroll
                for (int k = 0; k < 11; ++k) {
                    const int i = j + k + 3;
                    const float w = g[k];
                    a0 += w * xp[i];
                    a1 += w * xt[i];
                    a2 += w * pp[i];
                    a3 += w * tt[i];
                    a4 += w * pt[i];
                }
                hp[j]=a0; ht[j]=a1; hpp[j]=a2; htt[j]=a3; hpt[j]=a4;
            }
        }
        // vectorized stores (cseg is 8-aligned -> 16B aligned)
        {
            float4* d0 = (float4*)&s_h[0][hr][cseg];
            float4* d1 = (float4*)&s_h[1][hr][cseg];
            float4* d2 = (float4*)&s_h[2][hr][cseg];
            float4* d3 = (float4*)&s_h[3][hr][cseg];
            float4* d4 = (float4*)&s_h[4][hr][cseg];
            d0[0] = make_float4(hp[0],hp[1],hp[2],hp[3]);   d0[1] = make_float4(hp[4],hp[5],hp[6],hp[7]);
            d1[0] = make_float4(ht[0],ht[1],ht[2],ht[3]);   d1[1] = make_float4(ht[4],ht[5],ht[6],ht[7]);
            d2[0] = make_float4(hpp[0],hpp[1],hpp[2],hpp[3]); d2[1] = make_float4(hpp[4],hpp[5],hpp[6],hpp[7]);
            d3[0] = make_float4(htt[0],htt[1],htt[2],htt[3]); d3[1] = make_float4(htt[4],htt[5],htt[6],htt[7]);
            d4[0] = make_float4(hpt[0],hpt[1],hpt[2],hpt[3]); d4[1] = make_float4(hpt[4],hpt[5],hpt[6],hpt[7]);
        }
    }

    __syncthreads();

    // ---------- Phase 2: vertical conv + SSIM, LDS -> registers ----------
    // thread: col c = tid&63, row-group rg = tid>>6 -> output rows rg*8 .. rg*8+7
    const int c     = threadIdx.x & 63;
    const int rbase = (threadIdx.x >> 6) * 8;

    float acc[5][8];
#pragma unroll
    for (int q = 0; q < 5; ++q) {
        float v[18];
#pragma unroll
        for (int i = 0; i < 18; ++i) v[i] = s_h[q][rbase + i][c];   // stride-1 across lanes
#pragma unroll
        for (int i = 0; i < 8; ++i) {
            float a = 0.f;
#pragma unroll
            for (int k = 0; k < 11; ++k) a += g[k] * v[i + k];
            acc[q][i] = a;
        }
    }

    const float C1v = 0.0001f;   // 0.01^2
    const float C2v = 0.0009f;   // 0.03^2
    float local = 0.f;
#pragma unroll
    for (int i = 0; i < 8; ++i) {
        const float mu1  = acc[0][i];
        const float mu2  = acc[1][i];
        const float mu1s = mu1 * mu1;
        const float mu2s = mu2 * mu2;
        const float mu12 = mu1 * mu2;
        const float s1   = acc[2][i] - mu1s;
        const float s2   = acc[3][i] - mu2s;
        const float s12  = acc[4][i] - mu12;
        const float num  = (2.f * mu12 + C1v) * (2.f * s12 + C2v);
        const float den  = (mu1s + mu2s + C1v) * (s1 + s2 + C2v);
        local += num / den;
    }

    // ---------- Reduction ----------
#pragma unroll
    for (int off = 32; off > 0; off >>= 1) local += __shfl_down(local, off, 64);
    const int wave = threadIdx.x >> 6;
    if ((threadIdx.x & 63) == 0) s_red[wave] = local;
    __syncthreads();
    if (threadIdx.x == 0) {
        atomicAdd(accum, s_red[0] + s_red[1] + s_red[2] + s_red[3]);
    }
}

__global__ void ssim_finalize(const float* __restrict__ accum, float* __restrict__ out) {
    out[0] = 1.0f - accum[0] * (1.0f / N_TOTAL);
}

extern "C" void kernel_launch(void* const* d_in, const int* in_sizes, int n_in,
                              void* d_out, int out_size, void* d_ws, size_t ws_size,
                              hipStream_t stream) {
    const float* pred = (const float*)d_in[0];
    const float* targ = (const float*)d_in[1];
    float* out = (float*)d_out;
    float* ws  = (float*)d_ws;

    hipMemsetAsync(ws, 0, sizeof(float), stream);
    ssim_main<<<NBLOCKS, BLOCK, 0, stream>>>(pred, targ, ws);
    ssim_finalize<<<1, 1, 0, stream>>>(ws, out);
}